// Round 1
// baseline (247.949 us; speedup 1.0000x reference)
//
#include <hip/hip_runtime.h>
#include <hip/hip_bf16.h>
#include <stdint.h>

// Problem constants
#define B_SZ   1024
#define GF     512     // gating features
#define GC     63      // gate count
#define NLEAF  64
#define IN_F   512
#define OUT_F  512

typedef float f32x4 __attribute__((ext_vector_type(4)));
typedef __bf16 bf16x8 __attribute__((ext_vector_type(8)));

struct alignas(16) BV8 { __hip_bfloat162 a, b, c, d; };  // 8 bf16 = 16B

union BU { __hip_bfloat162 h; unsigned int u; };

// ---------------------------------------------------------------------------
// Kernel 1: gatings = sigmoid(x_gating @ gw + gb); leaf_probs via tree product
// One block (64 threads) per batch row.
// ---------------------------------------------------------------------------
__global__ __launch_bounds__(64, 4) void k_leafprobs(
    const float* __restrict__ xg, const float* __restrict__ gw,
    const float* __restrict__ gb, float* __restrict__ p_ws)
{
  __shared__ float xs[GF];
  __shared__ float gates[GC + 1];
  const int b = blockIdx.x;
  const int t = threadIdx.x;

  // stage x_gating row: 512 floats = 128 float4; 64 threads * 2 each
  {
    const float4* xrow = (const float4*)(xg + (size_t)b * GF);
    float4 v0 = xrow[t];
    float4 v1 = xrow[t + 64];
    *(float4*)&xs[t * 4]       = v0;
    *(float4*)&xs[256 + t * 4] = v1;
  }
  __syncthreads();

  if (t < GC) {
    float acc = gb[t];
#pragma unroll 4
    for (int k = 0; k < GF; ++k) acc += xs[k] * gw[k * GC + t];
    gates[t] = 1.f / (1.f + expf(-acc));
  }
  __syncthreads();

  // leaf product: child 2i has prob g, child 2i+1 has prob (1-g)
  float v = 1.f;
  int idx = 0, start = 0;
#pragma unroll
  for (int d = 0; d < 6; ++d) {
    int bit = (t >> (5 - d)) & 1;
    float g = gates[start + idx];
    v *= bit ? (1.f - g) : g;
    idx = 2 * idx + bit;
    start += (1 << d);
  }
  p_ws[(size_t)b * NLEAF + t] = v;
}

// ---------------------------------------------------------------------------
// Kernel 2: convert pw (fp32, [o][i][l]) -> pwb (bf16, [i][o][l])
// Pre-tiled so a GEMM B-tile (128 o-rows x 64 l for one i) is contiguous.
// ---------------------------------------------------------------------------
__global__ __launch_bounds__(256, 4) void k_convert(
    const float* __restrict__ pw, __hip_bfloat16* __restrict__ pwb)
{
  const int t  = blockIdx.x * 256 + threadIdx.x;   // 4,194,304 threads
  const int l4 = (t & 15) * 4;
  const int o  = (t >> 4) & 511;
  const int i  = t >> 13;

  float4 v = *(const float4*)(pw + ((size_t)o * IN_F + i) * NLEAF + l4);
  BU ua, ub;
  ua.h = __float22bfloat162_rn(make_float2(v.x, v.y));
  ub.h = __float22bfloat162_rn(make_float2(v.z, v.w));
  uint2 outv = make_uint2(ua.u, ub.u);
  *(uint2*)(pwb + (size_t)i * (OUT_F * NLEAF) + (size_t)o * NLEAF + l4) = outv;
}

// ---------------------------------------------------------------------------
// Kernel 3: out[b][o] = sum_l p[b][l] * pb[o][l]   (initializes d_out)
// ---------------------------------------------------------------------------
__global__ __launch_bounds__(256, 4) void k_bias(
    const float* __restrict__ p_ws, const float* __restrict__ pb,
    float* __restrict__ out)
{
  __shared__ float ps[NLEAF];
  const int b = blockIdx.x;
  const int t = threadIdx.x;
  if (t < NLEAF) ps[t] = p_ws[(size_t)b * NLEAF + t];
  __syncthreads();
#pragma unroll
  for (int rep = 0; rep < 2; ++rep) {
    int o = t + rep * 256;
    const float4* pbr = (const float4*)(pb + (size_t)o * NLEAF);
    float acc = 0.f;
#pragma unroll
    for (int l4 = 0; l4 < 16; ++l4) {
      float4 w = pbr[l4];
      acc += w.x * ps[l4*4] + w.y * ps[l4*4+1] + w.z * ps[l4*4+2] + w.w * ps[l4*4+3];
    }
    out[(size_t)b * OUT_F + o] = acc;
  }
}

// ---------------------------------------------------------------------------
// Kernel 4: main GEMM.  out[b][o] += sum_{i,l} (x[b][i]*p[b][l]) * pw[o][i][l]
// M=1024(b), N=512(o), K=32768 (k = i*64+l). 128x128 tiles, BK=64 (one i).
// Split-K=16 (512 blocks), fp32 atomicAdd epilogue.
// A-tile built on the fly: p in VGPRs, x slab in LDS, single RN round to bf16.
// B staged via global_load_lds width=16 with XOR-rotated per-lane source
// addresses so fragment ds_read_b128 hits the bank-floor (8 phases, not 16).
// ---------------------------------------------------------------------------
#define BM 128
#define BN 128
#define KSTEPS 32   // i-steps per k-chunk

__global__ __launch_bounds__(256, 2) void k_gemm(
    const float* __restrict__ x_leaf,          // [1024][512]
    const float* __restrict__ p_ws,            // [1024][64]
    const __hip_bfloat16* __restrict__ pwb,    // [512][512][64]  ([i][o][l])
    float* __restrict__ out)                   // [1024][512]
{
  __shared__ __align__(16) float           xs[BM][33];   // +1 pad: conflict-free bcast read
  __shared__ __align__(16) __hip_bfloat16  as[BM][72];   // +8 pad: 16B-aligned, 2-way max
  __shared__ __align__(16) __hip_bfloat16  bs[BN * 64];  // swizzled, glds target (no pad)

  const int tid  = threadIdx.x;
  const int lane = tid & 63;
  const int wid  = tid >> 6;        // 0..3
  const int quad = lane >> 4;       // 0..3
  const int l15  = lane & 15;

  const int bid = blockIdx.x;       // 512 blocks: mt fastest for L2 reuse of pwb
  const int mt = bid & 7;
  const int nt = (bid >> 3) & 3;
  const int kc = bid >> 5;          // 0..15

  const int row_m0 = mt * BM;       // batch-row base
  const int col_n0 = nt * BN;       // o base
  const int i0     = kc * KSTEPS;   // i base

  const int wm = (wid >> 1) * 64;   // wave's 64x64 quadrant
  const int wn = (wid & 1) * 64;

  // ---- stage x slab [128 rows][32 i] (scalar LDS stores, once) ----
  {
    int r = tid >> 1, h = tid & 1;
    const float* src = x_leaf + (size_t)(row_m0 + r) * IN_F + i0 + h * 16;
    float4 v0 = *(const float4*)(src + 0);
    float4 v1 = *(const float4*)(src + 4);
    float4 v2 = *(const float4*)(src + 8);
    float4 v3 = *(const float4*)(src + 12);
    float* d = &xs[r][h * 16];
    d[0]=v0.x; d[1]=v0.y; d[2]=v0.z; d[3]=v0.w;
    d[4]=v1.x; d[5]=v1.y; d[6]=v1.z; d[7]=v1.w;
    d[8]=v2.x; d[9]=v2.y; d[10]=v2.z; d[11]=v2.w;
    d[12]=v3.x; d[13]=v3.y; d[14]=v3.z; d[15]=v3.w;
  }

  // ---- p row-half into registers (row = tid>>1, l-half = (tid&1)*32) ----
  float preg[32];
  const int arow  = tid >> 1;
  const int ahalf = (tid & 1) * 32;
  {
    const float4* src = (const float4*)(p_ws + (size_t)(row_m0 + arow) * NLEAF + ahalf);
#pragma unroll
    for (int q8 = 0; q8 < 8; ++q8) {
      float4 v = src[q8];
      preg[q8*4+0] = v.x; preg[q8*4+1] = v.y;
      preg[q8*4+2] = v.z; preg[q8*4+3] = v.w;
    }
  }

  // ---- B-staging per-lane source offsets (XOR-rotated within each 128B row) ----
  // chunk = wid*4+v covers LDS rows n = chunk*8 .. +8; lane supplies block
  // q = (c - n) & 7 so the read-side addr n*128 + ((kblk+n)&7)*16 finds block kblk.
  size_t boff[4];
#pragma unroll
  for (int v = 0; v < 4; ++v) {
    int n = (wid * 4 + v) * 8 + (lane >> 3);
    int c = lane & 7;
    int q = (c - n) & 7;
    boff[v] = (size_t)(col_n0 + n) * NLEAF + q * 8;
  }

  f32x4 acc[4][4];
#pragma unroll
  for (int mi = 0; mi < 4; ++mi)
#pragma unroll
    for (int ni = 0; ni < 4; ++ni)
      acc[mi][ni] = (f32x4)(0.f);

  for (int ii = 0; ii < KSTEPS; ++ii) {
    __syncthreads();  // previous iteration's tiles fully consumed

    // -- async stage B tile (16 KB) for i = i0+ii --
    const __hip_bfloat16* gi = pwb + (size_t)(i0 + ii) * (OUT_F * NLEAF);
#pragma unroll
    for (int v = 0; v < 4; ++v) {
      __builtin_amdgcn_global_load_lds(
          (const __attribute__((address_space(1))) void*)(gi + boff[v]),
          (__attribute__((address_space(3))) void*)(&bs[(wid * 4 + v) * 512]),
          16, 0, 0);
    }

    // -- build A tile: as[b][l] = x[b][i] * p[b][l], single RN round --
    {
      float xv = xs[arow][ii];
#pragma unroll
      for (int w = 0; w < 4; ++w) {
        float f0 = xv * preg[w*8+0], f1 = xv * preg[w*8+1];
        float f2 = xv * preg[w*8+2], f3 = xv * preg[w*8+3];
        float f4 = xv * preg[w*8+4], f5 = xv * preg[w*8+5];
        float f6 = xv * preg[w*8+6], f7 = xv * preg[w*8+7];
        BV8 pk;
        pk.a = __float22bfloat162_rn(make_float2(f0, f1));
        pk.b = __float22bfloat162_rn(make_float2(f2, f3));
        pk.c = __float22bfloat162_rn(make_float2(f4, f5));
        pk.d = __float22bfloat162_rn(make_float2(f6, f7));
        *(BV8*)&as[arow][ahalf + w * 8] = pk;
      }
    }

    __syncthreads();  // drains vmcnt (glds) + lgkm (A writes)

    // -- compute: 2 k-steps of 32, 4x4 MFMAs each --
#pragma unroll
    for (int ks = 0; ks < 2; ++ks) {
      bf16x8 af[4], bf[4];
#pragma unroll
      for (int mi = 0; mi < 4; ++mi)
        af[mi] = *(const bf16x8*)&as[wm + mi * 16 + l15][ks * 32 + quad * 8];
#pragma unroll
      for (int ni = 0; ni < 4; ++ni) {
        int n = wn + ni * 16 + l15;
        int kblk = ks * 4 + quad;
        bf[ni] = *(const bf16x8*)&bs[n * 64 + (((kblk + n) & 7) << 3)];
      }
#pragma unroll
      for (int mi = 0; mi < 4; ++mi)
#pragma unroll
        for (int ni = 0; ni < 4; ++ni)
          acc[mi][ni] = __builtin_amdgcn_mfma_f32_16x16x32_bf16(
              af[mi], bf[ni], acc[mi][ni], 0, 0, 0);
    }
  }

  // ---- epilogue: atomic accumulate (split-K) ----
#pragma unroll
  for (int mi = 0; mi < 4; ++mi) {
#pragma unroll
    for (int ni = 0; ni < 4; ++ni) {
      int row = row_m0 + wm + mi * 16 + quad * 4;   // + reg gives C/D row
      int col = col_n0 + wn + ni * 16 + l15;        // C/D col = lane&15
      float* o0 = out + (size_t)row * OUT_F + col;
      atomicAdd(o0,             acc[mi][ni][0]);
      atomicAdd(o0 + OUT_F,     acc[mi][ni][1]);
      atomicAdd(o0 + 2 * OUT_F, acc[mi][ni][2]);
      atomicAdd(o0 + 3 * OUT_F, acc[mi][ni][3]);
    }
  }
}

// ---------------------------------------------------------------------------
extern "C" void kernel_launch(void* const* d_in, const int* in_sizes, int n_in,
                              void* d_out, int out_size, void* d_ws, size_t ws_size,
                              hipStream_t stream) {
  const float* xg = (const float*)d_in[0];   // x_gating [1024][512]
  const float* xl = (const float*)d_in[1];   // x_leaf   [1024][512]
  const float* gw = (const float*)d_in[2];   // [512][63]
  const float* gb = (const float*)d_in[3];   // [63]
  const float* pw = (const float*)d_in[4];   // [512][512][64]
  const float* pb = (const float*)d_in[5];   // [512][64]
  float* out = (float*)d_out;

  // workspace layout: pwb (bf16, 33.55 MB) | p (fp32, 256 KB)
  __hip_bfloat16* pwb = (__hip_bfloat16*)d_ws;
  float* p_ws = (float*)((char*)d_ws + (size_t)IN_F * OUT_F * NLEAF * sizeof(__hip_bfloat16));

  k_leafprobs<<<dim3(B_SZ), dim3(64), 0, stream>>>(xg, gw, gb, p_ws);
  k_convert<<<dim3(16384), dim3(256), 0, stream>>>(pw, pwb);
  k_bias<<<dim3(B_SZ), dim3(256), 0, stream>>>(p_ws, pb, out);
  k_gemm<<<dim3(512), dim3(256), 0, stream>>>(xl, p_ws, pwb, out);
}

// Round 2
// 208.004 us; speedup vs baseline: 1.1920x; 1.1920x over previous
//
#include <hip/hip_runtime.h>
#include <hip/hip_bf16.h>
#include <stdint.h>

// Problem constants
#define B_SZ   1024
#define GF     512     // gating features
#define GC     63      // gate count
#define NLEAF  64
#define IN_F   512
#define OUT_F  512

typedef float f32x4 __attribute__((ext_vector_type(4)));
typedef __bf16 bf16x8 __attribute__((ext_vector_type(8)));

struct alignas(16) BV8 { __hip_bfloat162 a, b, c, d; };  // 8 bf16 = 16B
union PK8 { BV8 v; bf16x8 f; };
union BU { __hip_bfloat162 h; unsigned int u; };

// ---------------------------------------------------------------------------
// Kernel 1: gatings = sigmoid(x_gating @ gw + gb); leaf_probs via tree product
// 512 threads / row: split-k=8 GEMV (coalesced gw rows) + LDS reduction.
// ---------------------------------------------------------------------------
__global__ __launch_bounds__(512, 2) void k_leafprobs(
    const float* __restrict__ xg, const float* __restrict__ gw,
    const float* __restrict__ gb, float* __restrict__ p_ws)
{
  __shared__ float xsr[GF];
  __shared__ float part[512];
  __shared__ float gates[GC + 1];
  const int b = blockIdx.x;
  const int t = threadIdx.x;

  xsr[t] = xg[(size_t)b * GF + t];
  __syncthreads();

  const int ks = t >> 6;    // 0..7  (k-split)
  const int g  = t & 63;    // gate
  float acc = 0.f;
  if (g < GC) {
    const float* gp = gw + (size_t)(ks * 64) * GC + g;
    const float* xp = &xsr[ks * 64];
#pragma unroll 8
    for (int k = 0; k < 64; ++k) acc += xp[k] * gp[(size_t)k * GC];
  }
  part[t] = acc;
  __syncthreads();

  if (t < GC) {
    float s = gb[t];
#pragma unroll
    for (int r = 0; r < 8; ++r) s += part[r * 64 + t];
    gates[t] = 1.f / (1.f + expf(-s));
  }
  __syncthreads();

  if (t < NLEAF) {
    float v = 1.f;
    int idx = 0, start = 0;
#pragma unroll
    for (int d = 0; d < 6; ++d) {
      int bit = (t >> (5 - d)) & 1;
      float gg = gates[start + idx];
      v *= bit ? (1.f - gg) : gg;
      idx = 2 * idx + bit;
      start += (1 << d);
    }
    p_ws[(size_t)b * NLEAF + t] = v;
  }
}

// ---------------------------------------------------------------------------
// Kernel 2: convert pw (fp32, [o][i][l]) -> pwb (bf16, [i][o][l])
// ---------------------------------------------------------------------------
__global__ __launch_bounds__(256, 4) void k_convert(
    const float* __restrict__ pw, __hip_bfloat16* __restrict__ pwb)
{
  const int t  = blockIdx.x * 256 + threadIdx.x;   // 4,194,304 threads
  const int l4 = (t & 15) * 4;
  const int o  = (t >> 4) & 511;
  const int i  = t >> 13;

  float4 v = *(const float4*)(pw + ((size_t)o * IN_F + i) * NLEAF + l4);
  BU ua, ub;
  ua.h = __float22bfloat162_rn(make_float2(v.x, v.y));
  ub.h = __float22bfloat162_rn(make_float2(v.z, v.w));
  uint2 outv = make_uint2(ua.u, ub.u);
  *(uint2*)(pwb + (size_t)i * (OUT_F * NLEAF) + (size_t)o * NLEAF + l4) = outv;
}

// ---------------------------------------------------------------------------
// Kernel 3: out[b][o] = sum_l p[b][l] * pb[o][l]   (initializes d_out)
// ---------------------------------------------------------------------------
__global__ __launch_bounds__(256, 4) void k_bias(
    const float* __restrict__ p_ws, const float* __restrict__ pb,
    float* __restrict__ out)
{
  __shared__ float ps[NLEAF];
  const int b = blockIdx.x;
  const int t = threadIdx.x;
  if (t < NLEAF) ps[t] = p_ws[(size_t)b * NLEAF + t];
  __syncthreads();
#pragma unroll
  for (int rep = 0; rep < 2; ++rep) {
    int o = t + rep * 256;
    const float4* pbr = (const float4*)(pb + (size_t)o * NLEAF);
    float acc = 0.f;
#pragma unroll
    for (int l4 = 0; l4 < 16; ++l4) {
      float4 w = pbr[l4];
      acc += w.x * ps[l4*4] + w.y * ps[l4*4+1] + w.z * ps[l4*4+2] + w.w * ps[l4*4+3];
    }
    out[(size_t)b * OUT_F + o] = acc;
  }
}

// ---------------------------------------------------------------------------
// Kernel 4: main GEMM.  out[b][o] += sum_{i,l} (x[b][i]*p[b][l]) * pw[o][i][l]
// M=1024(b), N=512(o), K=32768. 128x128 tiles, BK=64 (one i), split-K=16.
//
// R2 structure: A-operand built in REGISTERS (p held as 64 fp32/lane, x via
// LDS broadcast) -> no as[] tile, no second barrier. bs double-buffered with
// glds prefetch issued after each barrier: one __syncthreads per iteration,
// staging latency hidden behind the 32-MFMA compute phase.
// XCD swizzle: bid&7 -> (nt, kc&1) so each (nt,kc) B-combo lives on one XCD
// (pwb fetched ~once chip-wide); out-tile atomics confined to 2 XCDs.
// ---------------------------------------------------------------------------
#define BM 128
#define BN 128
#define KSTEPS 32   // i-steps per k-chunk

__global__ __launch_bounds__(256, 3) void k_gemm(
    const float* __restrict__ x_leaf,          // [1024][512]
    const float* __restrict__ p_ws,            // [1024][64]
    const __hip_bfloat16* __restrict__ pwb,    // [512][512][64]  ([i][o][l])
    float* __restrict__ out)                   // [1024][512]
{
  __shared__ __align__(16) float           xs[BM][33];      // 16.9 KB
  __shared__ __align__(16) __hip_bfloat16  bs[2][BN * 64];  // 2 x 16 KB

  const int tid  = threadIdx.x;
  const int lane = tid & 63;
  const int wid  = tid >> 6;        // 0..3
  const int quad = lane >> 4;       // 0..3
  const int l15  = lane & 15;

  // XCD-aware swizzle (8 XCDs, round-robin dispatch assumed; perf-only)
  const int bid = blockIdx.x;
  const int xcd = bid & 7;
  const int j   = bid >> 3;         // 0..63 within XCD
  const int nt  = xcd & 3;
  const int kcl = xcd >> 2;
  const int mt  = j & 7;
  const int kch = j >> 3;
  const int kc  = kch * 2 + kcl;    // 0..15

  const int row_m0 = mt * BM;
  const int col_n0 = nt * BN;
  const int i0     = kc * KSTEPS;

  const int wm = (wid >> 1) * 64;   // wave's 64x64 quadrant
  const int wn = (wid & 1) * 64;

  // ---- stage x slab [128 rows][32 i] ----
  {
    int r = tid >> 1, h = tid & 1;
    const float* src = x_leaf + (size_t)(row_m0 + r) * IN_F + i0 + h * 16;
    float4 v0 = *(const float4*)(src + 0);
    float4 v1 = *(const float4*)(src + 4);
    float4 v2 = *(const float4*)(src + 8);
    float4 v3 = *(const float4*)(src + 12);
    float* d = &xs[r][h * 16];
    d[0]=v0.x; d[1]=v0.y; d[2]=v0.z; d[3]=v0.w;
    d[4]=v1.x; d[5]=v1.y; d[6]=v1.z; d[7]=v1.w;
    d[8]=v2.x; d[9]=v2.y; d[10]=v2.z; d[11]=v2.w;
    d[12]=v3.x; d[13]=v3.y; d[14]=v3.z; d[15]=v3.w;
  }

  // ---- per-lane p fragment values, fp32 in registers: pr[mi][ks][half4] ----
  f32x4 pr[4][2][2];
#pragma unroll
  for (int mi = 0; mi < 4; ++mi) {
    int row = row_m0 + wm + mi * 16 + l15;
#pragma unroll
    for (int ks = 0; ks < 2; ++ks) {
      const f32x4* src = (const f32x4*)(p_ws + (size_t)row * NLEAF + ks * 32 + quad * 8);
      pr[mi][ks][0] = src[0];
      pr[mi][ks][1] = src[1];
    }
  }

  // ---- B-staging per-lane source offsets (XOR-rotated, as in R1) ----
  size_t boff[4];
#pragma unroll
  for (int v = 0; v < 4; ++v) {
    int n = (wid * 4 + v) * 8 + (lane >> 3);
    int c = lane & 7;
    int q = (c - n) & 7;
    boff[v] = (size_t)(col_n0 + n) * NLEAF + q * 8;
  }

  f32x4 acc[4][4];
#pragma unroll
  for (int mi = 0; mi < 4; ++mi)
#pragma unroll
    for (int ni = 0; ni < 4; ++ni)
      acc[mi][ni] = (f32x4)(0.f);

  // ---- prologue: stage B tile for ii=0 into buffer 0 ----
  {
    const __hip_bfloat16* gi = pwb + (size_t)i0 * (OUT_F * NLEAF);
#pragma unroll
    for (int v = 0; v < 4; ++v) {
      __builtin_amdgcn_global_load_lds(
          (const __attribute__((address_space(1))) void*)(gi + boff[v]),
          (__attribute__((address_space(3))) void*)(&bs[0][(wid * 4 + v) * 512]),
          16, 0, 0);
    }
  }

  for (int ii = 0; ii < KSTEPS; ++ii) {
    __syncthreads();   // drains glds(ii) [+ prologue stores on ii=0]; aligns buffers

    // -- prefetch: issue glds for tile ii+1 into the other buffer --
    if (ii < KSTEPS - 1) {
      const __hip_bfloat16* gi = pwb + (size_t)(i0 + ii + 1) * (OUT_F * NLEAF);
      __hip_bfloat16* dst = &bs[(ii + 1) & 1][0];
#pragma unroll
      for (int v = 0; v < 4; ++v) {
        __builtin_amdgcn_global_load_lds(
            (const __attribute__((address_space(1))) void*)(gi + boff[v]),
            (__attribute__((address_space(3))) void*)(dst + (wid * 4 + v) * 512),
            16, 0, 0);
      }
    }

    // -- x values for this i (LDS broadcast reads) --
    float xv[4];
#pragma unroll
    for (int mi = 0; mi < 4; ++mi) xv[mi] = xs[wm + mi * 16 + l15][ii];

    const __hip_bfloat16* bsc = &bs[ii & 1][0];

#pragma unroll
    for (int ks = 0; ks < 2; ++ks) {
      // build A fragments in registers: af = bf16(x * p), single RN round
      bf16x8 af[4];
#pragma unroll
      for (int mi = 0; mi < 4; ++mi) {
        f32x4 lo = pr[mi][ks][0] * xv[mi];
        f32x4 hi = pr[mi][ks][1] * xv[mi];
        PK8 u;
        u.v.a = __float22bfloat162_rn(make_float2(lo.x, lo.y));
        u.v.b = __float22bfloat162_rn(make_float2(lo.z, lo.w));
        u.v.c = __float22bfloat162_rn(make_float2(hi.x, hi.y));
        u.v.d = __float22bfloat162_rn(make_float2(hi.z, hi.w));
        af[mi] = u.f;
      }
#pragma unroll
      for (int ni = 0; ni < 4; ++ni) {
        int n = wn + ni * 16 + l15;
        int kblk = ks * 4 + quad;
        bf16x8 bfr = *(const bf16x8*)&bsc[n * 64 + (((kblk + n) & 7) << 3)];
#pragma unroll
        for (int mi = 0; mi < 4; ++mi)
          acc[mi][ni] = __builtin_amdgcn_mfma_f32_16x16x32_bf16(
              af[mi], bfr, acc[mi][ni], 0, 0, 0);
      }
    }
  }

  // ---- epilogue: atomic accumulate (split-K) ----
#pragma unroll
  for (int mi = 0; mi < 4; ++mi) {
#pragma unroll
    for (int ni = 0; ni < 4; ++ni) {
      int row = row_m0 + wm + mi * 16 + quad * 4;
      int col = col_n0 + wn + ni * 16 + l15;
      float* o0 = out + (size_t)row * OUT_F + col;
      atomicAdd(o0,             acc[mi][ni][0]);
      atomicAdd(o0 + OUT_F,     acc[mi][ni][1]);
      atomicAdd(o0 + 2 * OUT_F, acc[mi][ni][2]);
      atomicAdd(o0 + 3 * OUT_F, acc[mi][ni][3]);
    }
  }
}

// ---------------------------------------------------------------------------
extern "C" void kernel_launch(void* const* d_in, const int* in_sizes, int n_in,
                              void* d_out, int out_size, void* d_ws, size_t ws_size,
                              hipStream_t stream) {
  const float* xg = (const float*)d_in[0];   // x_gating [1024][512]
  const float* xl = (const float*)d_in[1];   // x_leaf   [1024][512]
  const float* gw = (const float*)d_in[2];   // [512][63]
  const float* gb = (const float*)d_in[3];   // [63]
  const float* pw = (const float*)d_in[4];   // [512][512][64]
  const float* pb = (const float*)d_in[5];   // [512][64]
  float* out = (float*)d_out;

  // workspace layout: pwb (bf16, 33.55 MB) | p (fp32, 256 KB)
  __hip_bfloat16* pwb = (__hip_bfloat16*)d_ws;
  float* p_ws = (float*)((char*)d_ws + (size_t)IN_F * OUT_F * NLEAF * sizeof(__hip_bfloat16));

  k_leafprobs<<<dim3(B_SZ), dim3(512), 0, stream>>>(xg, gw, gb, p_ws);
  k_convert<<<dim3(16384), dim3(256), 0, stream>>>(pw, pwb);
  k_bias<<<dim3(B_SZ), dim3(256), 0, stream>>>(p_ws, pb, out);
  k_gemm<<<dim3(512), dim3(256), 0, stream>>>(xl, p_ws, pwb, out);
}